// Round 5
// baseline (116.913 us; speedup 1.0000x reference)
//
#include <hip/hip_runtime.h>
#include <cstdint>

#define CKDIM 128
#define MDIM  4096
#define QDIM  4096
#define BATCH 4
#define MT    32                      // m-tiles of 128

typedef __attribute__((ext_vector_type(8))) _Float16 half8;
typedef __attribute__((ext_vector_type(4))) float    f32x4;

#if __has_builtin(__builtin_amdgcn_exp2f)
#define EXP2(x) __builtin_amdgcn_exp2f(x)
#else
#define EXP2(x) exp2f(x)
#endif

#define ALPHA 0.12753139626596757f    // log2(e)/sqrt(128)
#define K2A   0.25506279253193514f    // 2*ALPHA

__device__ inline void gl_lds16(const void* g, void* l) {
    __builtin_amdgcn_global_load_lds(
        (const __attribute__((address_space(1))) unsigned*)g,
        (__attribute__((address_space(3))) unsigned*)l, 16, 0, 0);
}

// ---- 1) fused transpose-convert: X[b][k][n] fp32 -> Xt[b][n][k] fp16,
//         and cm[b][m] = -ALPHA * sum_k Mk^2 (fp32-exact, pre-rounding).
__global__ void convert_kernel(const float* __restrict__ Mk, const float* __restrict__ Qk,
                               _Float16* __restrict__ At, _Float16* __restrict__ Bt,
                               float* __restrict__ cm) {
    __shared__ _Float16 T[128 * 130];
    __shared__ float    asqp[16][128];
    const int blk = blockIdx.x;                  // 256: mat(2) x b(4) x tile(32)
    const int mat = blk >> 7;
    const int b   = (blk >> 5) & 3;
    const int t   = blk & 31;
    const float*  src = (mat ? Qk : Mk) + (size_t)b * CKDIM * MDIM + t * 128;
    _Float16*     dst = (mat ? Bt : At) + ((size_t)b * MDIM + (size_t)t * 128) * CKDIM;
    const int tid = threadIdx.x;
    const int kg  = tid >> 4;
    const int ng  = tid & 15;

    float sq[8] = {0.f, 0.f, 0.f, 0.f, 0.f, 0.f, 0.f, 0.f};
    #pragma unroll
    for (int it = 0; it < 8; ++it) {
        int k = it * 16 + kg;
        const float* g = src + (size_t)k * MDIM + ng * 8;
        float4 v0 = *(const float4*)g;
        float4 v1 = *(const float4*)(g + 4);
        _Float16* p = &T[k * 130 + ng * 8];
        p[0] = (_Float16)v0.x; p[1] = (_Float16)v0.y; p[2] = (_Float16)v0.z; p[3] = (_Float16)v0.w;
        p[4] = (_Float16)v1.x; p[5] = (_Float16)v1.y; p[6] = (_Float16)v1.z; p[7] = (_Float16)v1.w;
        if (mat == 0) {
            sq[0] += v0.x * v0.x; sq[1] += v0.y * v0.y;
            sq[2] += v0.z * v0.z; sq[3] += v0.w * v0.w;
            sq[4] += v1.x * v1.x; sq[5] += v1.y * v1.y;
            sq[6] += v1.z * v1.z; sq[7] += v1.w * v1.w;
        }
    }
    if (mat == 0) {
        #pragma unroll
        for (int j = 0; j < 8; ++j) asqp[kg][ng * 8 + j] = sq[j];
    }
    __syncthreads();
    #pragma unroll
    for (int it = 0; it < 8; ++it) {
        int pid = it * 256 + tid;
        int n = pid >> 4, c = pid & 15;
        half8 o;
        #pragma unroll
        for (int j = 0; j < 8; ++j) o[j] = T[(c * 8 + j) * 130 + n];
        *(half8*)(dst + (size_t)n * CKDIM + c * 8) = o;
    }
    if (mat == 0 && tid < 128) {
        float s = 0.f;
        #pragma unroll
        for (int g = 0; g < 16; ++g) s += asqp[g][tid];
        cm[b * MDIM + t * 128 + tid] = -ALPHA * s;
    }
}

// ---- 2) fused softmax-GEMM: one block per (batch, 64-q stripe); B-tile in
//         registers; A-panel streamed twice (sum pass, write pass) with
//         double-buffered LDS and prefetch-before-compute.
__global__ __launch_bounds__(512, 2) void fused_kernel(
        const _Float16* __restrict__ At, const _Float16* __restrict__ Bt,
        const float* __restrict__ cmArr, float* __restrict__ out) {
    __shared__ __align__(16) char ldsB[16384];        // [64 q][128 k] fp16, swizzled
    __shared__ __align__(16) char ldsA[2][32768];     // [128 m][128 k] fp16, swizzled
    __shared__ float red[4][64];

    const int tid  = threadIdx.x;
    const int lane = tid & 63;
    const int wv   = tid >> 6;      // 0..7
    const int wr   = wv >> 1;       // m-row group (32 rows)
    const int qc   = wv & 1;        // q-col group (32 cols)
    const int g4   = lane >> 4;
    const int i    = lane & 15;

    const int wg = blockIdx.x;
    const int id = ((wg & 7) << 5) | (wg >> 3);   // XCD-chunked, bijective
    const int b  = id >> 6;
    const int q0 = (id & 63) << 6;

    const char* Ab = (const char*)(At + (size_t)b * MDIM * CKDIM);
    const char* Bb = (const char*)(Bt + ((size_t)b * QDIM + q0) * CKDIM);

    // stage B tile (16 KB) + A tile 0 (32 KB); linear dest, inv-swizzled source
    #pragma unroll
    for (int r = 0; r < 2; ++r) {
        unsigned Dw = (unsigned)(r * 8 + wv) * 1024;
        unsigned D  = Dw + (unsigned)lane * 16;
        unsigned S  = D ^ (((D >> 8) & 7u) << 4);
        gl_lds16(Bb + S, ldsB + Dw);
    }
    #pragma unroll
    for (int r = 0; r < 4; ++r) {
        unsigned Dw = (unsigned)(r * 8 + wv) * 1024;
        unsigned D  = Dw + (unsigned)lane * 16;
        unsigned S  = D ^ (((D >> 8) & 7u) << 4);
        gl_lds16(Ab + S, ldsA[0] + Dw);
    }
    asm volatile("s_waitcnt vmcnt(0)" ::: "memory");
    __syncthreads();

    // B fragments -> registers for the whole kernel
    half8 bfr[2][4];
    #pragma unroll
    for (int nf = 0; nf < 2; ++nf) {
        int n = qc * 32 + nf * 16 + i;
        #pragma unroll
        for (int t = 0; t < 4; ++t) {
            int kb = t * 64 + g4 * 16;
            bfr[nf][t] = *(const half8*)(ldsB + n * 256 + (kb ^ ((n & 7) << 4)));
        }
    }

    const size_t cmb = (size_t)b * MDIM;

    // ================= pass A: column sums =================
    float cs0 = 0.f, cs1 = 0.f;
    #pragma unroll 1
    for (int mt = 0; mt < MT; ++mt) {
        const char* lA = ldsA[mt & 1];
        f32x4 cm0 = *(const f32x4*)&cmArr[cmb + mt * 128 + wr * 32 + g4 * 4];
        f32x4 cm1 = *(const f32x4*)&cmArr[cmb + mt * 128 + wr * 32 + 16 + g4 * 4];
        if (mt + 1 < MT) {                        // prefetch next m-tile
            const char* Asrc = Ab + (size_t)(mt + 1) * 32768;
            #pragma unroll
            for (int r = 0; r < 4; ++r) {
                unsigned Dw = (unsigned)(r * 8 + wv) * 1024;
                unsigned D  = Dw + (unsigned)lane * 16;
                unsigned S  = D ^ (((D >> 8) & 7u) << 4);
                gl_lds16(Asrc + S, ldsA[(mt & 1) ^ 1] + Dw);
            }
        }
        f32x4 acc[2][2] = {};
        #pragma unroll
        for (int t = 0; t < 4; ++t) {
            int kb = t * 64 + g4 * 16;
            int n0 = wr * 32 + i, n1 = wr * 32 + 16 + i;
            half8 a0 = *(const half8*)(lA + n0 * 256 + (kb ^ ((n0 & 7) << 4)));
            half8 a1 = *(const half8*)(lA + n1 * 256 + (kb ^ ((n1 & 7) << 4)));
            acc[0][0] = __builtin_amdgcn_mfma_f32_16x16x32_f16(a0, bfr[0][t], acc[0][0], 0, 0, 0);
            acc[0][1] = __builtin_amdgcn_mfma_f32_16x16x32_f16(a0, bfr[1][t], acc[0][1], 0, 0, 0);
            acc[1][0] = __builtin_amdgcn_mfma_f32_16x16x32_f16(a1, bfr[0][t], acc[1][0], 0, 0, 0);
            acc[1][1] = __builtin_amdgcn_mfma_f32_16x16x32_f16(a1, bfr[1][t], acc[1][1], 0, 0, 0);
        }
        #pragma unroll
        for (int r = 0; r < 4; ++r) {
            cs0 += EXP2(fmaf(acc[0][0][r], K2A, cm0[r]));
            cs1 += EXP2(fmaf(acc[0][1][r], K2A, cm0[r]));
            cs0 += EXP2(fmaf(acc[1][0][r], K2A, cm1[r]));
            cs1 += EXP2(fmaf(acc[1][1][r], K2A, cm1[r]));
        }
        __syncthreads();                          // prefetch lands here
    }

    // reduce column sums: across g4 (shfl), then across wr (LDS)
    cs0 += __shfl_xor(cs0, 16); cs0 += __shfl_xor(cs0, 32);
    cs1 += __shfl_xor(cs1, 16); cs1 += __shfl_xor(cs1, 32);
    if (lane < 16) {
        red[wr][qc * 32 + lane]      = cs0;
        red[wr][qc * 32 + 16 + lane] = cs1;
    }
    __syncthreads();
    float rs0, rs1;
    {
        int q = qc * 32 + i;
        rs0 = 1.0f / (red[0][q] + red[1][q] + red[2][q] + red[3][q]);
        q += 16;
        rs1 = 1.0f / (red[0][q] + red[1][q] + red[2][q] + red[3][q]);
    }
    __syncthreads();

    // re-prime A tile 0
    #pragma unroll
    for (int r = 0; r < 4; ++r) {
        unsigned Dw = (unsigned)(r * 8 + wv) * 1024;
        unsigned D  = Dw + (unsigned)lane * 16;
        unsigned S  = D ^ (((D >> 8) & 7u) << 4);
        gl_lds16(Ab + S, ldsA[0] + Dw);
    }
    asm volatile("s_waitcnt vmcnt(0)" ::: "memory");
    __syncthreads();

    // ================= pass B: recompute + write =================
    #pragma unroll 1
    for (int mt = 0; mt < MT; ++mt) {
        const char* lA = ldsA[mt & 1];
        f32x4 cm0 = *(const f32x4*)&cmArr[cmb + mt * 128 + wr * 32 + g4 * 4];
        f32x4 cm1 = *(const f32x4*)&cmArr[cmb + mt * 128 + wr * 32 + 16 + g4 * 4];
        if (mt + 1 < MT) {
            const char* Asrc = Ab + (size_t)(mt + 1) * 32768;
            #pragma unroll
            for (int r = 0; r < 4; ++r) {
                unsigned Dw = (unsigned)(r * 8 + wv) * 1024;
                unsigned D  = Dw + (unsigned)lane * 16;
                unsigned S  = D ^ (((D >> 8) & 7u) << 4);
                gl_lds16(Asrc + S, ldsA[(mt & 1) ^ 1] + Dw);
            }
        }
        f32x4 acc[2][2] = {};
        #pragma unroll
        for (int t = 0; t < 4; ++t) {
            int kb = t * 64 + g4 * 16;
            int n0 = wr * 32 + i, n1 = wr * 32 + 16 + i;
            half8 a0 = *(const half8*)(lA + n0 * 256 + (kb ^ ((n0 & 7) << 4)));
            half8 a1 = *(const half8*)(lA + n1 * 256 + (kb ^ ((n1 & 7) << 4)));
            acc[0][0] = __builtin_amdgcn_mfma_f32_16x16x32_f16(a0, bfr[0][t], acc[0][0], 0, 0, 0);
            acc[0][1] = __builtin_amdgcn_mfma_f32_16x16x32_f16(a0, bfr[1][t], acc[0][1], 0, 0, 0);
            acc[1][0] = __builtin_amdgcn_mfma_f32_16x16x32_f16(a1, bfr[0][t], acc[1][0], 0, 0, 0);
            acc[1][1] = __builtin_amdgcn_mfma_f32_16x16x32_f16(a1, bfr[1][t], acc[1][1], 0, 0, 0);
        }
        #pragma unroll
        for (int mf = 0; mf < 2; ++mf) {
            int    mrow = mt * 128 + wr * 32 + mf * 16 + g4 * 4;
            f32x4  cmv  = mf ? cm1 : cm0;
            size_t base = (((size_t)b * MDIM + mrow) << 12) + (q0 + qc * 32 + i);
            #pragma unroll
            for (int nf = 0; nf < 2; ++nf) {
                float rs = nf ? rs1 : rs0;
                size_t bq = base + nf * 16;
                #pragma unroll
                for (int r = 0; r < 4; ++r) {
                    float e = EXP2(fmaf(acc[mf][nf][r], K2A, cmv[r])) * rs;
                    __builtin_nontemporal_store(e, &out[bq + ((size_t)r << 12)]);
                }
            }
        }
        __syncthreads();
    }
}

extern "C" void kernel_launch(void* const* d_in, const int* in_sizes, int n_in,
                              void* d_out, int out_size, void* d_ws, size_t ws_size,
                              hipStream_t stream) {
    const float* Mk = (const float*)d_in[0];
    const float* Qk = (const float*)d_in[1];
    float* out = (float*)d_out;

    _Float16* At = (_Float16*)d_ws;                             // 4 MB
    _Float16* Bt = At + (size_t)BATCH * MDIM * CKDIM;           // 4 MB
    float*    cm = (float*)(Bt + (size_t)BATCH * MDIM * CKDIM); // 64 KB

    convert_kernel<<<256, 256, 0, stream>>>(Mk, Qk, At, Bt, cm);
    fused_kernel<<<256, 512, 0, stream>>>(At, Bt, cm, out);
}